// Round 9
// baseline (375.851 us; speedup 1.0000x reference)
//
#include <hip/hip_runtime.h>
#include <hip/hip_bf16.h>
#include <hip/hip_fp16.h>

#define N_NODES 100000
#define R_REL   7
#define E_EDGES 1600000
#define EDIM    16
#define KTOT    640    // 448 msg + 64 self + 112 F + 7 sw + 9 pad  (B layout, K dim)
#define AROWB   1280   // A-tile row stride in BYTES (640 bf16): 16 rows = 20480B
                       // -> 8 blocks/CU (LDS). Bank conflicts: row-XOR swizzle.
#define CAP     56     // slots per node; P(deg>55 | Binom(1.6M,1e-5)) ~ 4e-10
#define CSTR    16     // cnt stride in ints: one counter per 64B line
#define CHUNK   16     // records per vmcnt-drain window (R7 guard-free padding)
#define NPART   8      // scatter partitions ~ XCDs (blockIdx%8 -> XCD under
                       // round-robin dispatch; PERF-only assumption, not corr.)
#define NPP     12500  // nodes per partition
#define BPP     256    // blocks per partition (grid 2048)
#define EPB     (E_EDGES / BPP)   // 6250 edges scanned per block

// recs8 layout: SLOT-MAJOR recs8[slot*N + dst] (R8, k_main depends on it).
// R8 falsified "slot-band L2 residency" for the UNPARTITIONED scatter: random
// CUs on 8 non-coherent XCD L2s share each line -> 8 dirty copies, 118MB WB.
// R9: partition by dst range; all writers of a line sit on ONE XCD -> line
// written 8x in-cache, evicted once. cnt slice 800KB + slot band ~500KB fit L2.

// swizzle: byte offset within row XOR'd with (row&7)<<4 (verified R4/R6/R7)
#define ASWZ(row, cb) ((row) * AROWB + ((cb) ^ (((row) & 7) << 4)))

typedef __bf16 bf16_t;
typedef bf16_t bf16x8 __attribute__((ext_vector_type(8)));
typedef float  f32x4  __attribute__((ext_vector_type(4)));
typedef unsigned long long u64;

#define RFL(v) __builtin_amdgcn_readfirstlane(v)
#define RL(v, l) __builtin_amdgcn_readlane(v, l)

// ---------------- fused prep + XCD-partitioned scatter ----------------------
// record (8B): u0 = src(17b) | rel(3b)<<17 | e[0:12)<<20
//              u1 = e[12:21) | (f32(w) & 0xFFFFFE00)

__global__ __launch_bounds__(256) void k_pre(
    const float* __restrict__ x, const int* __restrict__ el,
    const float* __restrict__ wgt,
    const float* __restrict__ W_lin, const float* __restrict__ W_self,
    const float* __restrict__ W_edge, const float* __restrict__ b_edge,
    int* __restrict__ cnt, bf16_t* __restrict__ xb, bf16_t* __restrict__ Bp,
    u64* __restrict__ recs8)
{
    const int t = blockIdx.x * 256 + threadIdx.x;

    // ---- x -> bf16, 16 floats per thread (400000 threads of 524288) ----
    if (t < (N_NODES * 64) / 16) {
        const float4* xp = (const float4*)(x + (size_t)t * 16);
        float4 v0 = xp[0], v1 = xp[1], v2 = xp[2], v3 = xp[3];
        bf16x8 o0 = {(bf16_t)v0.x, (bf16_t)v0.y, (bf16_t)v0.z, (bf16_t)v0.w,
                     (bf16_t)v1.x, (bf16_t)v1.y, (bf16_t)v1.z, (bf16_t)v1.w};
        bf16x8 o1 = {(bf16_t)v2.x, (bf16_t)v2.y, (bf16_t)v2.z, (bf16_t)v2.w,
                     (bf16_t)v3.x, (bf16_t)v3.y, (bf16_t)v3.z, (bf16_t)v3.w};
        *(bf16x8*)(xb + (size_t)t * 16)     = o0;
        *(bf16x8*)(xb + (size_t)t * 16 + 8) = o1;
    }

    // ---- pack B (40960 threads) ----
    // B[k][j]: k<448 W_lin[j][k]; 448..511 W_self; 512..623 (W_lin_r@W_edge);
    // 624..630 (W_lin_r@b_edge); 631..639 zero.  Bp[((k/8)*64 + j)*8 + (k%8)]
    if (t < KTOT * 64) {
        int k = t >> 6;
        int j = t & 63;
        float v;
        if (k < 448) {
            v = W_lin[j * 448 + k];
        } else if (k < 512) {
            v = W_self[j * 64 + (k - 448)];
        } else if (k < 624) {
            int r = (k - 512) >> 4, kk = (k - 512) & 15;
            float sacc = 0.f;
            for (int d = 0; d < 64; d++)
                sacc = fmaf(W_lin[j * 448 + r * 64 + d], W_edge[d * 16 + kk], sacc);
            v = sacc;
        } else if (k < 631) {
            int r = k - 624;
            float sacc = 0.f;
            for (int d = 0; d < 64; d++)
                sacc = fmaf(W_lin[j * 448 + r * 64 + d], b_edge[d], sacc);
            v = sacc;
        } else {
            v = 0.f;
        }
        Bp[((k >> 3) * 64 + j) * 8 + (k & 7)] = (bf16_t)v;
    }

    // ---- partitioned scatter: part = blockIdx%8 owns dst in [part*NPP, +NPP)
    // The BPP blocks of a part together scan ALL edges (el/wgt are L3-resident
    // so the 8x scan is L3-fed); hits (~1/8) do an L2-LOCAL atomic + store.
    {
        const int part   = blockIdx.x & (NPART - 1);
        const int pbase  = part * NPP;
        const int estart = (blockIdx.x >> 3) * EPB;
        for (int e = estart + threadIdx.x; e < estart + EPB; e += 256) {
            const int dst = el[e * 3 + 1];
            if ((unsigned)(dst - pbase) < (unsigned)NPP) {
                const int src = el[e * 3];
                const int rel = el[e * 3 + 2];
                const float w = wgt[e];
                const int slot = atomicAdd(&cnt[dst * CSTR], 1);
                unsigned u0 = (unsigned)src | ((unsigned)rel << 17)
                            | ((unsigned)(e & 0xFFF) << 20);
                unsigned u1 = ((unsigned)e >> 12)
                            | (__float_as_uint(w) & 0xFFFFFE00u);
                if (slot < CAP)
                    recs8[(size_t)slot * N_NODES + dst] = ((u64)u1 << 32) | u0;
            }
        }
    }
}

// ---------------- fused gather/segment-sum + MFMA GEMM ----------------------
// Stage 1 (verified R7/R8): per node, rel-sort records in-register (7 ballots
// -> rank = prefix[rel] + mbcnt -> ds_permute), pad with (rel=7,w=0) dummies,
// then guard-free CHUNK=16 issue/consume windows (arrays stay in registers).
// Window load slot-major: recs8[lane * N + n].  BYTE-IDENTICAL TO R8.

__global__ __launch_bounds__(256, 6) void k_main(
    const bf16_t* __restrict__ xb, const float* __restrict__ ef,
    const float* __restrict__ b_lin, const float* __restrict__ b_self,
    const int* __restrict__ cnt, const u64* __restrict__ recs8,
    const bf16_t* __restrict__ Bp, float* __restrict__ out)
{
    __shared__ __align__(16) unsigned char A[16 * AROWB];  // 20 KB exactly
    const int wave = threadIdx.x >> 6;
    const int lane = threadIdx.x & 63;
    const int lef  = lane & 15;
    const int nodeBase = blockIdx.x * 16;
    const int n0 = nodeBase + wave * 4;

    int md[4];
    u64 rw[4];
#pragma unroll
    for (int i = 0; i < 4; i++) {
        const int row = wave * 4 + i;
        md[i] = RFL(min(cnt[(n0 + i) * CSTR], CAP));
        rw[i] = (lane < md[i]) ? recs8[(size_t)lane * N_NODES + (n0 + i)] : 0ull;
        *(bf16_t*)(A + ASWZ(row, (448 + lane) * 2)) = xb[(n0 + i) * 64 + lane];
        uint4 z = {0u, 0u, 0u, 0u};
        if (lane < 56) *(uint4*)(A + ASWZ(row, lane * 16)) = z;
        if (lane < 16) *(uint4*)(A + ASWZ(row, 1024 + lane * 16)) = z;
    }

#pragma unroll
    for (int i = 0; i < 4; i++) {
        const int row = wave * 4 + i;
        const int m = md[i];
        if (m == 0) continue;                        // wave-uniform skip
        const int u0v = (int)(unsigned)rw[i];
        const int u1v = (int)(unsigned)(rw[i] >> 32);
        const int relv = ((unsigned)u0v >> 17) & 7;
        const bool valid = lane < m;

        // ---- in-register sort by rel (verified R6/R7) ----
        u64 g0 = __ballot(valid && relv == 0);
        u64 g1 = __ballot(valid && relv == 1);
        u64 g2 = __ballot(valid && relv == 2);
        u64 g3 = __ballot(valid && relv == 3);
        u64 g4 = __ballot(valid && relv == 4);
        u64 g5 = __ballot(valid && relv == 5);
        u64 g6 = __ballot(valid && relv == 6);
        const int c0 = __builtin_popcountll(g0), c1 = __builtin_popcountll(g1);
        const int c2 = __builtin_popcountll(g2), c3 = __builtin_popcountll(g3);
        const int c4 = __builtin_popcountll(g4), c5 = __builtin_popcountll(g5);
        const int p0 = 0, p1 = c0, p2 = p1 + c1, p3 = p2 + c2;
        const int p4 = p3 + c3, p5 = p4 + c4, p6 = p5 + c5;
        const bool b0 = relv & 1, b1 = relv & 2, b2 = relv & 4;
        u64 t0 = b0 ? g1 : g0, t1 = b0 ? g3 : g2, t2 = b0 ? g5 : g4, t3 = g6;
        u64 sA = b1 ? t1 : t0, sB = b1 ? t3 : t2;
        u64 mm = b2 ? sB : sA;
        int pa = b0 ? p1 : p0, pb = b0 ? p3 : p2, pc = b0 ? p5 : p4, pd = p6;
        int pe_ = b1 ? pb : pa, pf_ = b1 ? pd : pc;
        int pfx = b2 ? pf_ : pe_;
        int rig = __builtin_amdgcn_mbcnt_hi((unsigned)(mm >> 32),
                  __builtin_amdgcn_mbcnt_lo((unsigned)mm, 0));
        int rank = valid ? (pfx + rig) : lane;       // bijective 0..63
        const int pv0 = valid ? u0v : (7 << 17);
        const int pv1 = valid ? u1v : 0;
        const int su0 = __builtin_amdgcn_ds_permute(rank * 4, pv0);
        const int su1 = __builtin_amdgcn_ds_permute(rank * 4, pv1);

        // ---- guard-free chunked issue/consume over the padded stream ----
        float a = 0.f, F = 0.f, sw_ = 0.f;
        int cur = -1;
        for (int base = 0; base < m; base += CHUNK) {
            unsigned short xv[CHUNK];
            float ev[CHUNK], wk[CHUNK];
            int rk[CHUNK];
#pragma unroll
            for (int k = 0; k < CHUNK; k++) {        // unconditional: regs
                const int uu0 = RL(su0, base + k);
                const int uu1 = RL(su1, base + k);
                const int src = uu0 & 0x1FFFF;
                const int e   = (int)(((unsigned)uu0) >> 20)
                              | ((uu1 & 0x1FF) << 12);
                rk[k] = (int)((((unsigned)uu0) >> 17) & 7);
                wk[k] = __uint_as_float((unsigned)uu1 & 0xFFFFFE00u);
                xv[k] = *(const unsigned short*)(xb + ((size_t)src << 6) + lane);
                ev[k] = ef[(size_t)e * EDIM + lef];
            }
#pragma unroll
            for (int k = 0; k < CHUNK; k++) {        // unconditional: regs
                if (rk[k] != cur && rk[k] != 7) {    // scalar rel boundary
                    if (cur >= 0) {
                        *(bf16_t*)(A + ASWZ(row, (cur * 64 + lane) * 2)) = (bf16_t)a;
                        if (lane < EDIM)
                            *(bf16_t*)(A + ASWZ(row, (512 + cur * EDIM + lane) * 2)) = (bf16_t)F;
                        if (lane == 0)
                            *(bf16_t*)(A + ASWZ(row, (624 + cur) * 2)) = (bf16_t)sw_;
                    }
                    a = 0.f; F = 0.f; sw_ = 0.f; cur = rk[k];
                }
                const float xf = __uint_as_float(((unsigned)xv[k]) << 16);
                a   = fmaf(wk[k], xf,    a);         // dummies: w=0, exact no-op
                F   = fmaf(wk[k], ev[k], F);
                sw_ += wk[k];
            }
        }
        // final flush (m>0 guarantees cur>=0)
        *(bf16_t*)(A + ASWZ(row, (cur * 64 + lane) * 2)) = (bf16_t)a;
        if (lane < EDIM)
            *(bf16_t*)(A + ASWZ(row, (512 + cur * EDIM + lane) * 2)) = (bf16_t)F;
        if (lane == 0)
            *(bf16_t*)(A + ASWZ(row, (624 + cur) * 2)) = (bf16_t)sw_;
    }
    __syncthreads();

    // stage 2: MFMA over K=640 (swizzled A reads; verified R4/R6/R7/R8)
    const int quad = lane >> 4;
    const int l15  = lane & 15;
    const unsigned abase = (unsigned)l15 * AROWB;
    const unsigned aswz  = (unsigned)((l15 & 7) << 4);
    f32x4 c = {0.f, 0.f, 0.f, 0.f};
#pragma unroll
    for (int s2i = 0; s2i < KTOT / 32; s2i++) {
        bf16x8 av = *(const bf16x8*)(A + abase
                     + (((unsigned)(s2i * 64 + quad * 16)) ^ aswz));
        bf16x8 bv = *(const bf16x8*)(Bp + (((s2i * 4 + quad) * 64) + wave * 16 + l15) * 8);
        c = __builtin_amdgcn_mfma_f32_16x16x32_bf16(av, bv, c, 0, 0, 0);
    }
    const int j = wave * 16 + l15;
    const float bias = b_lin[j] + b_self[j];
#pragma unroll
    for (int q = 0; q < 4; q++) {
        const int n = nodeBase + quad * 4 + q;
        float v = c[q] + bias;
        out[n * 64 + j] = v > 0.f ? v : 0.f;
    }
}

// ---------------- launch ----------------------------------------------------

extern "C" void kernel_launch(void* const* d_in, const int* in_sizes, int n_in,
                              void* d_out, int out_size, void* d_ws, size_t ws_size,
                              hipStream_t stream) {
    const float* x      = (const float*)d_in[0];
    const int*   el     = (const int*)  d_in[1];
    const float* wgt    = (const float*)d_in[2];
    const float* ef     = (const float*)d_in[3];
    const float* W_lin  = (const float*)d_in[4];
    const float* b_lin  = (const float*)d_in[5];
    const float* W_self = (const float*)d_in[6];
    const float* b_self = (const float*)d_in[7];
    const float* W_edge = (const float*)d_in[8];
    const float* b_edge = (const float*)d_in[9];
    float* out = (float*)d_out;

    // workspace: recs8(44.8M, slot-major) | cnt(6.4M padded) | xb(12.8M) | Bp(80K)
    u64*    recs8 = (u64*)d_ws;
    int*    cnt   = (int*)(recs8 + (size_t)N_NODES * CAP);
    bf16_t* xb    = (bf16_t*)(cnt + (size_t)N_NODES * CSTR);
    bf16_t* Bp    = xb + (size_t)N_NODES * 64;

    hipMemsetAsync(cnt, 0, (size_t)N_NODES * CSTR * sizeof(int), stream);
    k_pre <<<NPART * BPP, 256, 0, stream>>>(x, el, wgt, W_lin, W_self, W_edge,
                                            b_edge, cnt, xb, Bp, recs8);
    k_main<<<N_NODES / 16, 256, 0, stream>>>(xb, ef, b_lin, b_self,
                                             cnt, recs8, Bp, out);
}